// Round 1
// baseline (301.438 us; speedup 1.0000x reference)
//
#include <hip/hip_runtime.h>
#include <math.h>

// TemporalMotor: per-sample keyframe interpolation.
//   inputs : t (N,), translations (64,3), quaternions (64,4), keyframe_times (64,)
//   outputs: trans (N,3) then quat (N,4), concatenated flat in d_out (float32)
//
// Memory-bound op: ~33.5 MB read + ~235 MB write => ~43 us floor @ 6.3 TB/s.

#define KFR 64          // number of keyframes (fixed by harness setup)
#define BLOCK 256

__global__ __launch_bounds__(BLOCK) void temporal_motor_kernel(
    const float* __restrict__ t_in,          // (N,)
    const float* __restrict__ translations,  // (KFR,3)
    const float* __restrict__ quaternions,   // (KFR,4)
    const float* __restrict__ keyframe_times,// (KFR,)
    float* __restrict__ out_trans,           // (N,3) flat
    float* __restrict__ out_quat,            // (N,4) flat
    int n4)                                  // N/4
{
    // Staged keyframe tables.
    //   s_q[k] = normalized quaternion k
    //   s_t[k] = (trans.x, trans.y, trans.z, keyframe_time)
    __shared__ float4 s_q[KFR];
    __shared__ float4 s_t[KFR];

    const int tid = threadIdx.x;
    if (tid < KFR) {
        float qx = quaternions[4 * tid + 0];
        float qy = quaternions[4 * tid + 1];
        float qz = quaternions[4 * tid + 2];
        float qw = quaternions[4 * tid + 3];
        float nrm = sqrtf(qx * qx + qy * qy + qz * qz + qw * qw);
        float inv = 1.0f / fmaxf(nrm, 1e-12f);   // ref: q / clip(norm, 1e-12)
        s_q[tid] = make_float4(qx * inv, qy * inv, qz * inv, qw * inv);
        s_t[tid] = make_float4(translations[3 * tid + 0],
                               translations[3 * tid + 1],
                               translations[3 * tid + 2],
                               keyframe_times[tid]);
    }
    __syncthreads();

    const float4* __restrict__ t4 = (const float4*)t_in;
    const int stride = gridDim.x * blockDim.x;

    for (int i = blockIdx.x * blockDim.x + tid; i < n4; i += stride) {
        float4 tv = t4[i];

        float trx[4], try_[4], trz[4];
        float4 oq[4];

        #pragma unroll
        for (int j = 0; j < 4; ++j) {
            float tt = (j == 0) ? tv.x : (j == 1) ? tv.y : (j == 2) ? tv.z : tv.w;

            // --- searchsorted(keyframe_times, tt, 'left') then clip(1, 63) ---
            // keyframe_times is linspace(0,1,64): arithmetic guess, then exact
            // fixup against the real float32 table values (handles boundary
            // rounding; loops execute ~0 iterations in practice).
            int g = (int)ceilf(tt * (float)(KFR - 1));
            g = (g < 1) ? 1 : (g > KFR - 1) ? KFR - 1 : g;
            float4 tp = s_t[g - 1];
            float4 tn = s_t[g];
            while (g > 1 && tp.w >= tt) { --g; tn = tp; tp = s_t[g - 1]; }
            while (g < KFR - 1 && tn.w < tt) { ++g; tp = tn; tn = s_t[g]; }

            float lt  = (tt - tp.w) / (tn.w - tp.w + 1e-8f);
            float omt = 1.0f - lt;

            // --- translation lerp: (1-lt)*prev + lt*next ---
            trx[j] = omt * tp.x + lt * tn.x;
            try_[j] = omt * tp.y + lt * tn.y;
            trz[j] = omt * tp.z + lt * tn.z;

            // --- quaternion slerp (shortest arc, nlerp fallback) ---
            float4 q0 = s_q[g - 1];
            float4 q1 = s_q[g];
            float d = q0.x * q1.x + q0.y * q1.y + q0.z * q1.z + q0.w * q1.w;
            float sgn = (d < 0.0f) ? -1.0f : 1.0f;   // take shortest path
            q1.x *= sgn; q1.y *= sgn; q1.z *= sgn; q1.w *= sgn;
            d = fminf(fabsf(d), 1.0f);               // clip(abs(dot), -1, 1)

            float theta = acosf(d);
            float st2   = fmaxf(1.0f - d * d, 0.0f);
            float st    = sqrtf(st2);                // sin(theta), theta in [0, pi/2]
            float invst = (st < 1e-8f) ? 1.0f : (1.0f / st);

            float s0 = __sinf(omt * theta) * invst;
            float s1 = __sinf(lt * theta) * invst;

            float sx = s0 * q0.x + s1 * q1.x;
            float sy = s0 * q0.y + s1 * q1.y;
            float sz = s0 * q0.z + s1 * q1.z;
            float sw = s0 * q0.w + s1 * q1.w;

            // nlerp fallback: normalize(q0 + lt*(q1-q0))
            float lx = q0.x + lt * (q1.x - q0.x);
            float ly = q0.y + lt * (q1.y - q0.y);
            float lz = q0.z + lt * (q1.z - q0.z);
            float lw = q0.w + lt * (q1.w - q0.w);
            float ln = sqrtf(lx * lx + ly * ly + lz * lz + lw * lw);
            float li = 1.0f / fmaxf(ln, 1e-12f);

            bool fb = (d > 0.9995f);
            oq[j] = fb ? make_float4(lx * li, ly * li, lz * li, lw * li)
                       : make_float4(sx, sy, sz, sw);
        }

        // --- coalesced stores: 3x float4 trans, 4x float4 quat ---
        float4* ot = (float4*)(out_trans + (size_t)i * 12);
        ot[0] = make_float4(trx[0], try_[0], trz[0], trx[1]);
        ot[1] = make_float4(try_[1], trz[1], trx[2], try_[2]);
        ot[2] = make_float4(trz[2], trx[3], try_[3], trz[3]);

        float4* oqp = (float4*)(out_quat + (size_t)i * 16);
        oqp[0] = oq[0]; oqp[1] = oq[1]; oqp[2] = oq[2]; oqp[3] = oq[3];
    }
}

// Scalar tail kernel (defensive; N is expected to be divisible by 4).
__global__ void temporal_motor_tail(
    const float* __restrict__ t_in,
    const float* __restrict__ translations,
    const float* __restrict__ quaternions,
    const float* __restrict__ keyframe_times,
    float* __restrict__ out_trans,
    float* __restrict__ out_quat,
    int n_start, int n)
{
    int i = n_start + blockIdx.x * blockDim.x + threadIdx.x;
    if (i >= n) return;
    float tt = t_in[i];

    // linear search (tiny tail only)
    int g = 1;
    while (g < KFR - 1 && keyframe_times[g] < tt) ++g;
    float tpw = keyframe_times[g - 1], tnw = keyframe_times[g];
    float lt = (tt - tpw) / (tnw - tpw + 1e-8f);
    float omt = 1.0f - lt;

    for (int c = 0; c < 3; ++c)
        out_trans[3 * (size_t)i + c] =
            omt * translations[3 * (g - 1) + c] + lt * translations[3 * g + c];

    float q0[4], q1[4];
    float n0 = 0, n1 = 0;
    for (int c = 0; c < 4; ++c) { q0[c] = quaternions[4 * (g - 1) + c]; n0 += q0[c] * q0[c]; }
    for (int c = 0; c < 4; ++c) { q1[c] = quaternions[4 * g + c];       n1 += q1[c] * q1[c]; }
    float i0 = 1.0f / fmaxf(sqrtf(n0), 1e-12f), i1 = 1.0f / fmaxf(sqrtf(n1), 1e-12f);
    float d = 0;
    for (int c = 0; c < 4; ++c) { q0[c] *= i0; q1[c] *= i1; }
    for (int c = 0; c < 4; ++c) d += q0[c] * q1[c];
    float sgn = (d < 0.0f) ? -1.0f : 1.0f;
    for (int c = 0; c < 4; ++c) q1[c] *= sgn;
    d = fminf(fabsf(d), 1.0f);
    float theta = acosf(d);
    float st = sqrtf(fmaxf(1.0f - d * d, 0.0f));
    float invst = (st < 1e-8f) ? 1.0f : (1.0f / st);
    float s0 = __sinf(omt * theta) * invst, s1 = __sinf(lt * theta) * invst;
    float l[4], ln = 0;
    for (int c = 0; c < 4; ++c) { l[c] = q0[c] + lt * (q1[c] - q0[c]); ln += l[c] * l[c]; }
    float li = 1.0f / fmaxf(sqrtf(ln), 1e-12f);
    bool fb = (d > 0.9995f);
    for (int c = 0; c < 4; ++c)
        out_quat[4 * (size_t)i + c] = fb ? l[c] * li : (s0 * q0[c] + s1 * q1[c]);
}

extern "C" void kernel_launch(void* const* d_in, const int* in_sizes, int n_in,
                              void* d_out, int out_size, void* d_ws, size_t ws_size,
                              hipStream_t stream) {
    const float* t_in  = (const float*)d_in[0];
    const float* trans = (const float*)d_in[1];
    const float* quats = (const float*)d_in[2];
    const float* ktime = (const float*)d_in[3];
    const int N = in_sizes[0];

    float* out_trans = (float*)d_out;
    float* out_quat  = (float*)d_out + (size_t)N * 3;

    const int n4 = N / 4;
    int blocks = (n4 + BLOCK - 1) / BLOCK;
    if (blocks > 2048) blocks = 2048;   // grid-stride; amortize LDS table load
    if (blocks < 1) blocks = 1;

    if (n4 > 0)
        temporal_motor_kernel<<<blocks, BLOCK, 0, stream>>>(
            t_in, trans, quats, ktime, out_trans, out_quat, n4);

    const int rem_start = n4 * 4;
    if (rem_start < N) {
        int rem = N - rem_start;
        temporal_motor_tail<<<(rem + 63) / 64, 64, 0, stream>>>(
            t_in, trans, quats, ktime, out_trans, out_quat, rem_start, N);
    }
}

// Round 2
// 262.355 us; speedup vs baseline: 1.1490x; 1.1490x over previous
//
#include <hip/hip_runtime.h>
#include <math.h>

// TemporalMotor: per-sample keyframe interpolation.
//   inputs : t (N,), translations (64,3), quaternions (64,4), keyframe_times (64,)
//   outputs: trans (N,3) then quat (N,4), concatenated flat in d_out (float32)
//
// Memory-bound: ~33.5 MB read + ~235 MB write => ~41 us floor @ 6.5 TB/s.
// Strategy:
//   * per-block prologue precomputes PER-SEGMENT records (63 segments):
//     normalized quats, sign-fixed q1, d, theta, 1/sin(theta), nlerp flag,
//     trans prev/delta, 1/dt  -> acosf runs 63x/block, not 8.4Mx.
//   * wave-interleaved element ownership: lane l, sub-elem j -> idx = base+j*64+l
//     so every load/store instruction is lane-contiguous (perfect coalescing).
//   * per element: 1x __sincosf + identity s0 = cos(lt*th) - d*s1; branch-free
//     slerp/nlerp weight select (fallback is a segment property).

#define KFR   64
#define NSEG  63
#define BLOCK 256
#define CHUNK 1024   // elements per block-iteration (256 threads * 4)

__global__ __launch_bounds__(BLOCK) void temporal_motor_kernel(
    const float* __restrict__ t_in,
    const float* __restrict__ translations,
    const float* __restrict__ quaternions,
    const float* __restrict__ keyframe_times,
    float* __restrict__ out_trans,
    float* __restrict__ out_quat,
    int nchunks)
{
    // Per-segment records (SoA of float4, indexed by segment s = 0..62):
    //   sA[s] = (t_prev, t_next, 1/(dt+1e-8), theta)
    //   sB[s] = (trans_prev.xyz, inv_sin_theta or 0)
    //   sC[s] = (trans_delta.xyz, d)            d = clip(|dot|,0,1)
    //   sQ0[s], sQ1[s] = unit quats, q1 sign-fixed for shortest arc
    __shared__ float4 sA[KFR];
    __shared__ float4 sB[KFR];
    __shared__ float4 sC[KFR];
    __shared__ float4 sQ0[KFR];
    __shared__ float4 sQ1[KFR];

    const int tid = threadIdx.x;
    if (tid < NSEG) {
        const int s = tid;
        float t0 = keyframe_times[s];
        float t1 = keyframe_times[s + 1];

        float ax = quaternions[4 * s + 0], ay = quaternions[4 * s + 1];
        float az = quaternions[4 * s + 2], aw = quaternions[4 * s + 3];
        float bx = quaternions[4 * s + 4], by = quaternions[4 * s + 5];
        float bz = quaternions[4 * s + 6], bw = quaternions[4 * s + 7];
        float ia = 1.0f / fmaxf(sqrtf(ax * ax + ay * ay + az * az + aw * aw), 1e-12f);
        float ib = 1.0f / fmaxf(sqrtf(bx * bx + by * by + bz * bz + bw * bw), 1e-12f);
        ax *= ia; ay *= ia; az *= ia; aw *= ia;
        bx *= ib; by *= ib; bz *= ib; bw *= ib;

        float d0 = ax * bx + ay * by + az * bz + aw * bw;
        float sgn = (d0 < 0.0f) ? -1.0f : 1.0f;          // shortest arc
        bx *= sgn; by *= sgn; bz *= sgn; bw *= sgn;
        float d = fminf(fabsf(d0), 1.0f);                // clip(|dot|, -1, 1)

        float theta = acosf(d);
        float st    = sqrtf(fmaxf(1.0f - d * d, 0.0f));
        float inv_st = (d > 0.9995f) ? 0.0f : (1.0f / st);  // 0 marks nlerp seg

        float px = translations[3 * s + 0], py = translations[3 * s + 1];
        float pz = translations[3 * s + 2];
        float nx = translations[3 * s + 3], ny = translations[3 * s + 4];
        float nz = translations[3 * s + 5];

        sA[s]  = make_float4(t0, t1, 1.0f / (t1 - t0 + 1e-8f), theta);
        sB[s]  = make_float4(px, py, pz, inv_st);
        sC[s]  = make_float4(nx - px, ny - py, nz - pz, d);
        sQ0[s] = make_float4(ax, ay, az, aw);
        sQ1[s] = make_float4(bx, by, bz, bw);
    }
    __syncthreads();

    const int lane = tid & 63;
    const int wave = tid >> 6;

    for (int chunk = blockIdx.x; chunk < nchunks; chunk += gridDim.x) {
        const int base = chunk * CHUNK + wave * 256 + lane;

        #pragma unroll
        for (int j = 0; j < 4; ++j) {
            const int idx = base + j * 64;      // lane-contiguous per instruction
            const float tt = t_in[idx];

            // --- segment search: searchsorted-left, clipped; arithmetic guess
            //     + exact fixup against the real table values ---
            int s = (int)ceilf(tt * (float)NSEG) - 1;
            s = (s < 0) ? 0 : (s > NSEG - 1) ? NSEG - 1 : s;
            float4 a = sA[s];
            while (s > 0 && a.x >= tt)        { --s; a = sA[s]; }
            while (s < NSEG - 1 && a.y < tt)  { ++s; a = sA[s]; }

            const float lt  = (tt - a.x) * a.z;
            const float omt = 1.0f - lt;

            const float4 b = sB[s];
            const float4 c = sC[s];

            // --- translation: prev + lt*delta ---
            float3 tr;
            tr.x = fmaf(lt, c.x, b.x);
            tr.y = fmaf(lt, c.y, b.y);
            tr.z = fmaf(lt, c.z, b.z);

            // --- quat weights: slerp via identity, nlerp fallback; branch-free ---
            float sn, cs;
            __sincosf(lt * a.w, &sn, &cs);
            const float d   = c.w;
            const float wbs = sn * b.w;              // sin(lt*th)/sin(th)
            const float was = cs - d * wbs;          // == sin((1-lt)*th)/sin(th)

            const float s2  = fmaf(-2.0f * lt * omt, 1.0f - d, 1.0f); // |nlerp|^2
            const float inv = rsqrtf(fmaxf(s2, 1e-24f));
            const float wal = omt * inv;
            const float wbl = lt * inv;

            const bool fb = (d > 0.9995f);
            const float wa = fb ? wal : was;
            const float wb = fb ? wbl : wbs;

            const float4 q0 = sQ0[s];
            const float4 q1 = sQ1[s];
            float4 oq;
            oq.x = wa * q0.x + wb * q1.x;
            oq.y = wa * q0.y + wb * q1.y;
            oq.z = wa * q0.z + wb * q1.z;
            oq.w = wa * q0.w + wb * q1.w;

            // --- perfectly coalesced stores ---
            *(float3*)(out_trans + (size_t)idx * 3) = tr;   // 768 B / wave-inst
            *(float4*)(out_quat  + (size_t)idx * 4) = oq;   // 1 KB / wave-inst
        }
    }
}

// Scalar fallback (tail elements, or K != 64).
__global__ void temporal_motor_tail(
    const float* __restrict__ t_in,
    const float* __restrict__ translations,
    const float* __restrict__ quaternions,
    const float* __restrict__ keyframe_times,
    float* __restrict__ out_trans,
    float* __restrict__ out_quat,
    int n_start, int n, int K)
{
    int i = n_start + blockIdx.x * blockDim.x + threadIdx.x;
    if (i >= n) return;
    float tt = t_in[i];

    int g = 1;
    while (g < K - 1 && keyframe_times[g] < tt) ++g;
    float tpw = keyframe_times[g - 1], tnw = keyframe_times[g];
    float lt = (tt - tpw) / (tnw - tpw + 1e-8f);
    float omt = 1.0f - lt;

    for (int c = 0; c < 3; ++c)
        out_trans[3 * (size_t)i + c] =
            omt * translations[3 * (g - 1) + c] + lt * translations[3 * g + c];

    float q0[4], q1[4];
    float n0 = 0, n1 = 0;
    for (int c = 0; c < 4; ++c) { q0[c] = quaternions[4 * (g - 1) + c]; n0 += q0[c] * q0[c]; }
    for (int c = 0; c < 4; ++c) { q1[c] = quaternions[4 * g + c];       n1 += q1[c] * q1[c]; }
    float i0 = 1.0f / fmaxf(sqrtf(n0), 1e-12f), i1 = 1.0f / fmaxf(sqrtf(n1), 1e-12f);
    float d = 0;
    for (int c = 0; c < 4; ++c) { q0[c] *= i0; q1[c] *= i1; }
    for (int c = 0; c < 4; ++c) d += q0[c] * q1[c];
    float sgn = (d < 0.0f) ? -1.0f : 1.0f;
    for (int c = 0; c < 4; ++c) q1[c] *= sgn;
    d = fminf(fabsf(d), 1.0f);
    float theta = acosf(d);
    float st = sqrtf(fmaxf(1.0f - d * d, 0.0f));
    float invst = (st < 1e-8f) ? 1.0f : (1.0f / st);
    float s0 = __sinf(omt * theta) * invst, s1 = __sinf(lt * theta) * invst;
    float l[4], ln = 0;
    for (int c = 0; c < 4; ++c) { l[c] = q0[c] + lt * (q1[c] - q0[c]); ln += l[c] * l[c]; }
    float li = 1.0f / fmaxf(sqrtf(ln), 1e-12f);
    bool fb = (d > 0.9995f);
    for (int c = 0; c < 4; ++c)
        out_quat[4 * (size_t)i + c] = fb ? l[c] * li : (s0 * q0[c] + s1 * q1[c]);
}

extern "C" void kernel_launch(void* const* d_in, const int* in_sizes, int n_in,
                              void* d_out, int out_size, void* d_ws, size_t ws_size,
                              hipStream_t stream) {
    const float* t_in  = (const float*)d_in[0];
    const float* trans = (const float*)d_in[1];
    const float* quats = (const float*)d_in[2];
    const float* ktime = (const float*)d_in[3];
    const int N = in_sizes[0];
    const int K = in_sizes[3];

    float* out_trans = (float*)d_out;
    float* out_quat  = (float*)d_out + (size_t)N * 3;

    if (K == KFR) {
        const int nchunks = N / CHUNK;
        if (nchunks > 0) {
            int blocks = nchunks < 2048 ? nchunks : 2048;  // grid-stride
            temporal_motor_kernel<<<blocks, BLOCK, 0, stream>>>(
                t_in, trans, quats, ktime, out_trans, out_quat, nchunks);
        }
        const int rem_start = nchunks * CHUNK;
        if (rem_start < N) {
            int rem = N - rem_start;
            temporal_motor_tail<<<(rem + 63) / 64, 64, 0, stream>>>(
                t_in, trans, quats, ktime, out_trans, out_quat, rem_start, N, K);
        }
    } else {
        temporal_motor_tail<<<(N + 255) / 256, 256, 0, stream>>>(
            t_in, trans, quats, ktime, out_trans, out_quat, 0, N, K);
    }
}